// Round 8
// baseline (276.946 us; speedup 1.0000x reference)
//
#include <hip/hip_runtime.h>
#include <hip/hip_bf16.h>
#include <math.h>

#define Bq   8
#define DINq 256
#define Nq   2048

typedef __attribute__((ext_vector_type(8))) short bf16x8v;
typedef __attribute__((ext_vector_type(4))) float f32x4v;

__device__ __forceinline__ unsigned short f2bf(float f) {
  union { float f; unsigned u; } v; v.f = f;
  unsigned r = v.u + 0x7fffu + ((v.u >> 16) & 1u);
  return (unsigned short)(r >> 16);
}
__device__ __forceinline__ float bf2f(unsigned short h) {
  union { unsigned u; float f; } v; v.u = ((unsigned)h) << 16;
  return v.f;
}

__device__ __forceinline__ void gld_lds16(const void* g, void* l) {
  __builtin_amdgcn_global_load_lds(
      (const __attribute__((address_space(1))) unsigned int*)g,
      (__attribute__((address_space(3))) unsigned int*)l, 16, 0, 0);
}

// ---- w123[k] = (W^T a1)[k], (W^T a2)[k], (W^T a3)[k] ----
__global__ void k_prep(const float* __restrict__ W, const float* __restrict__ a,
                       float* __restrict__ w123) {
  int k = threadIdx.x;
  float s1 = 0.f, s2 = 0.f, s3 = 0.f;
  for (int d = 0; d < DINq; ++d) {
    float w = W[d * DINq + k];
    s1 += w * a[d];
    s2 += w * a[DINq + d];
    s3 += w * a[2 * DINq + d];
  }
  w123[k] = s1; w123[DINq + k] = s2; w123[2 * DINq + k] = s3;
}

// ---- WT[k][d] = W[d][k] ----
__global__ void k_transposeW(const float* __restrict__ W, float* __restrict__ WT) {
  int d = blockIdx.x, k = threadIdx.x;
  WT[(size_t)k * DINq + d] = W[(size_t)d * DINq + k];
}

// ---- X^T[(b,d)][i] = t[b,i]*h[b,i,d] hi/lo bf16; fused t/si/sb. NO h array. ----
__global__ __launch_bounds__(256, 2) void k_hX(const float* __restrict__ x,
                     const float* __restrict__ WT, const float* __restrict__ w123,
                     unsigned short* __restrict__ Xhi, unsigned short* __restrict__ Xlo,
                     float* __restrict__ tA, float* __restrict__ siA,
                     float* __restrict__ sbA) {
  __shared__ float xs[64][32];      // 8 KB   (k x i)
  __shared__ float ws[64][128];     // 32 KB  (k x d-half)
  __shared__ float wls[3][256];     // 3 KB
  __shared__ float Pd[3][16][32];   // 6 KB
  __shared__ float Tt[32];
  const int tid = threadIdx.x;
  const int iq = tid & 15;          // 2 i's each
  const int dg = tid >> 4;          // 16 groups of 8 d's (within d-half)
  const int i0 = blockIdx.x * 32;
  const int b = blockIdx.y;

  for (int n = tid; n < 768; n += 256) ((float*)wls)[n] = w123[n];

  float p1[2] = {0.f, 0.f}, p2[2] = {0.f, 0.f}, p3[2] = {0.f, 0.f};

#pragma unroll
  for (int dh = 0; dh < 2; ++dh) {
    float acc[2][8];
#pragma unroll
    for (int aa = 0; aa < 2; ++aa)
#pragma unroll
      for (int cc = 0; cc < 8; ++cc) acc[aa][cc] = 0.f;

    for (int kc = 0; kc < 4; ++kc) {
      __syncthreads();
#pragma unroll
      for (int n = 0; n < 8; ++n) {
        int idx = n * 256 + tid;
        int kk = idx >> 5, ii = idx & 31;
        xs[kk][ii] = x[((size_t)b * DINq + kc * 64 + kk) * Nq + i0 + ii];
      }
#pragma unroll
      for (int n = 0; n < 8; ++n) {
        int idx = n * 256 + tid;
        int kk = idx >> 5, c4 = (idx & 31) * 4;
        *(f32x4v*)&ws[kk][c4] =
            *(const f32x4v*)&WT[(size_t)(kc * 64 + kk) * DINq + dh * 128 + c4];
      }
      __syncthreads();
#pragma unroll 4
      for (int kk = 0; kk < 64; ++kk) {
        float xv0 = xs[kk][iq * 2], xv1 = xs[kk][iq * 2 + 1];
        f32x4v w0 = *(const f32x4v*)&ws[kk][dg * 8];
        f32x4v w1 = *(const f32x4v*)&ws[kk][dg * 8 + 4];
#pragma unroll
        for (int cc = 0; cc < 4; ++cc) {
          acc[0][cc]     += xv0 * w0[cc];
          acc[0][cc + 4] += xv0 * w1[cc];
          acc[1][cc]     += xv1 * w0[cc];
          acc[1][cc + 4] += xv1 * w1[cc];
        }
      }
      if (dh == 0) {
#pragma unroll
        for (int kap = 0; kap < 4; ++kap) {
          int kk = dg * 4 + kap;
          float xv0 = xs[kk][iq * 2], xv1 = xs[kk][iq * 2 + 1];
          float w3 = wls[2][kc * 64 + kk];
          float w1v = wls[0][kc * 64 + kk], w2v = wls[1][kc * 64 + kk];
          p3[0] += xv0 * w3;  p3[1] += xv1 * w3;
          p1[0] += xv0 * w1v; p1[1] += xv1 * w1v;
          p2[0] += xv0 * w2v; p2[1] += xv1 * w2v;
        }
      }
    }

    if (dh == 0) {
#pragma unroll
      for (int aa = 0; aa < 2; ++aa) {
        Pd[0][dg][iq * 2 + aa] = p1[aa];
        Pd[1][dg][iq * 2 + aa] = p2[aa];
        Pd[2][dg][iq * 2 + aa] = p3[aa];
      }
      __syncthreads();
      if (tid < 32) {
        float t = 0.f, s1 = 0.f, s2 = 0.f;
#pragma unroll
        for (int g = 0; g < 16; ++g) {
          s1 += Pd[0][g][tid]; s2 += Pd[1][g][tid]; t += Pd[2][g][tid];
        }
        Tt[tid] = t;
        tA[(size_t)b * Nq + i0 + tid] = t;
        siA[(size_t)b * Nq + i0 + tid] = s1;
        sbA[(size_t)b * Nq + i0 + tid] = s2;
      }
      __syncthreads();
    }

    const float tv0 = Tt[iq * 2], tv1 = Tt[iq * 2 + 1];
#pragma unroll
    for (int cc = 0; cc < 8; ++cc) {
      int d = dh * 128 + dg * 8 + cc;
      float X0 = tv0 * acc[0][cc];
      float X1 = tv1 * acc[1][cc];
      unsigned short h0 = f2bf(X0), h1 = f2bf(X1);
      unsigned short l0 = f2bf(X0 - bf2f(h0)), l1 = f2bf(X1 - bf2f(h1));
      size_t xoff = ((size_t)b * DINq + d) * Nq + i0 + iq * 2;
      *(ushort2*)&Xhi[xoff] = make_ushort2(h0, h1);
      *(ushort2*)&Xlo[xoff] = make_ushort2(l0, l1);
    }
  }
}

// ---- Mb[i][j] = (adj!=0 && i!=j) ? 1.0bf16 : 0 ; bm = adj!=0 bitmask ----
__global__ void k_mask(const int* __restrict__ adj, unsigned short* __restrict__ Mb,
                       unsigned* __restrict__ bm) {
  int wg = blockIdx.x * 256 + threadIdx.x;
  int i = wg >> 6, w = wg & 63, j0 = w * 32;
  const int4* ap = (const int4*)&adj[(size_t)i * Nq + j0];
  unsigned bits = 0;
  unsigned short mv[32];
#pragma unroll
  for (int q = 0; q < 8; ++q) {
    int4 a = ap[q];
    int av[4] = {a.x, a.y, a.z, a.w};
#pragma unroll
    for (int e = 0; e < 4; ++e) {
      int j = j0 + q * 4 + e;
      bool nz = (av[e] != 0);
      if (nz) bits |= 1u << (q * 4 + e);
      mv[q * 4 + e] = (nz && j != i) ? (unsigned short)0x3F80 : (unsigned short)0;
    }
  }
  ushort4* mp = (ushort4*)&Mb[(size_t)i * Nq + j0];
#pragma unroll
  for (int q = 0; q < 8; ++q)
    mp[q] = make_ushort4(mv[q * 4], mv[q * 4 + 1], mv[q * 4 + 2], mv[q * 4 + 3]);
  bm[wg] = bits;
}

// ---- GEMM: tile 256(M)x128(C), BK=32 tri-buffer counted vmcnt, K-split x2,
//      z-split hi/lo, XCD-swizzled grid, fused sjv-partial epilogue (X-based) ----
__global__ __launch_bounds__(256, 2) void k_gemm(const unsigned short* __restrict__ Mb,
                                                 const unsigned short* __restrict__ Xhi,
                                                 const unsigned short* __restrict__ Xlo,
                                                 float* __restrict__ sjp) {
  __shared__ __align__(16) unsigned short As[3][256 * 32];
  __shared__ __align__(16) unsigned short Bs[3][128 * 32];
  const int tid = threadIdx.x;
  const int lane = tid & 63;
  const int wave = tid >> 6;
  const int wm = wave >> 1, wc = wave & 1;
  const int wg = blockIdx.x;
  const int lin = (wg & 7) * 64 + (wg >> 3);
  const int mt = lin >> 6;
  const int rem = lin & 63;
  const int ks = rem >> 5;
  const int z = (rem >> 4) & 1;
  const int ct = rem & 15;
  const int i0 = mt * 256, c0 = ct * 128, kbase = ks * 1024;
  const unsigned short* __restrict__ Xp = z ? Xlo : Xhi;
  const int r15 = lane & 15, kg = lane >> 4;
  const int kb = 16 * (kg ^ ((r15 >> 1) & 3));

  f32x4v acc[8][4];
#pragma unroll
  for (int m = 0; m < 8; ++m)
#pragma unroll
    for (int n = 0; n < 4; ++n) acc[m][n] = (f32x4v)0.f;

  auto STAGE = [&](int buf, int t) {
    const int k0 = kbase + t * 32;
#pragma unroll
    for (int l = 0; l < 4; ++l) {
      const int pc = l * 256 + tid;
      const int row = pc >> 2, q = pc & 3;
      const int kc = 8 * (q ^ ((row >> 1) & 3));
      gld_lds16(&Mb[(size_t)(i0 + row) * Nq + k0 + kc], &As[buf][pc * 8]);
    }
#pragma unroll
    for (int l = 0; l < 2; ++l) {
      const int pc = l * 256 + tid;
      const int row = pc >> 2, q = pc & 3;
      const int kc = 8 * (q ^ ((row >> 1) & 3));
      gld_lds16(&Xp[(size_t)(c0 + row) * Nq + k0 + kc], &Bs[buf][pc * 8]);
    }
  };

  constexpr int NT = 32;  // 1024 / 32
  STAGE(0, 0);
  STAGE(1, 1);
  int cb = 0, sb2 = 2;
  for (int t = 0; t < NT; ++t) {
    if (t + 1 < NT) {
      asm volatile("s_waitcnt vmcnt(6)" ::: "memory");
    } else {
      asm volatile("s_waitcnt vmcnt(0)" ::: "memory");
    }
    __builtin_amdgcn_sched_barrier(0);
    __builtin_amdgcn_s_barrier();
    __builtin_amdgcn_sched_barrier(0);
    if (t + 2 < NT) STAGE(sb2, t + 2);

    const char* Ab = (const char*)&As[cb][0];
    const char* Bb = (const char*)&Bs[cb][0];
    bf16x8v af[8], bf[4];
#pragma unroll
    for (int m = 0; m < 8; ++m)
      af[m] = *(const bf16x8v*)(Ab + (wm * 128 + m * 16 + r15) * 64 + kb);
#pragma unroll
    for (int n = 0; n < 4; ++n)
      bf[n] = *(const bf16x8v*)(Bb + (wc * 64 + n * 16 + r15) * 64 + kb);
    __builtin_amdgcn_s_setprio(1);
#pragma unroll
    for (int m = 0; m < 8; ++m)
#pragma unroll
      for (int n = 0; n < 4; ++n)
        acc[m][n] = __builtin_amdgcn_mfma_f32_16x16x32_bf16(af[m], bf[n], acc[m][n], 0, 0, 0);
    __builtin_amdgcn_s_setprio(0);
    cb = (cb == 2) ? 0 : cb + 1;
    sb2 = (sb2 == 2) ? 0 : sb2 + 1;
  }

  const int b = c0 >> 8;
  const int re = (lane >> 4) * 4, ce = lane & 15;
  float s[8][4];
#pragma unroll
  for (int m = 0; m < 8; ++m)
#pragma unroll
    for (int r = 0; r < 4; ++r) s[m][r] = 0.f;
#pragma unroll
  for (int n = 0; n < 4; ++n) {
    const size_t xrow = (size_t)(c0 + wc * 64 + n * 16 + ce) * Nq;
#pragma unroll
    for (int m = 0; m < 8; ++m) {
      const size_t ib = xrow + i0 + wm * 128 + m * 16 + re;
      ushort4 xh = *(const ushort4*)&Xhi[ib];
      ushort4 xl = *(const ushort4*)&Xlo[ib];
      s[m][0] += acc[m][n][0] * (bf2f(xh.x) + bf2f(xl.x));
      s[m][1] += acc[m][n][1] * (bf2f(xh.y) + bf2f(xl.y));
      s[m][2] += acc[m][n][2] * (bf2f(xh.z) + bf2f(xl.z));
      s[m][3] += acc[m][n][3] * (bf2f(xh.w) + bf2f(xl.w));
    }
  }
#pragma unroll
  for (int o = 1; o < 16; o <<= 1) {
#pragma unroll
    for (int m = 0; m < 8; ++m)
#pragma unroll
      for (int r = 0; r < 4; ++r) s[m][r] += __shfl_xor(s[m][r], o, 64);
  }
  if (ce == 0) {
    const int slice = ks * 8 + z * 4 + (ct & 1) * 2 + wc;
    float* sp = sjp + ((size_t)slice * Bq + b) * Nq;
#pragma unroll
    for (int m = 0; m < 8; ++m)
#pragma unroll
      for (int r = 0; r < 4; ++r)
        sp[i0 + wm * 128 + m * 16 + re + r] = s[m][r];
  }
}

// ---- sjv[b,i] = sb[b,i] + (sum of 16 partial slices) / t[b,i] ----
__global__ void k_sjsum(const float* __restrict__ sbA, const float* __restrict__ tA,
                        const float* __restrict__ sjp, float* __restrict__ sjvA) {
  int idx = blockIdx.x * 256 + threadIdx.x;
  float s = 0.f;
#pragma unroll
  for (int sl = 0; sl < 16; ++sl) s += sjp[(size_t)sl * Bq * Nq + idx];
  sjvA[idx] = sbA[idx] + s / tA[idx];
}

// ---- out[b,i,:] = softmax_j( mask(bm, lrelu(si[b,i] + sjv[b,j])) ) ----
__global__ void k_softmax(const unsigned* __restrict__ bm, const float* __restrict__ siA,
                          const float* __restrict__ sjvA, float* __restrict__ out) {
  const int b = blockIdx.y, i = blockIdx.x, tid = threadIdx.x;
  const float siv = siA[(size_t)b * Nq + i];
  const unsigned* brow = bm + (size_t)i * 64;
  const float* sjb = sjvA + (size_t)b * Nq;
  const int bit = tid & 31;
  float sc[8];
  float mx = -3.0e38f;
#pragma unroll
  for (int s = 0; s < 8; ++s) {
    int j = s * 256 + tid;
    float v = siv + sjb[j];
    v = v > 0.f ? v : 0.2f * v;
    unsigned wv = brow[j >> 5];
    v = ((wv >> bit) & 1u) ? v : -9.0e15f;
    sc[s] = v;
    mx = fmaxf(mx, v);
  }
#pragma unroll
  for (int o = 32; o >= 1; o >>= 1) mx = fmaxf(mx, __shfl_xor(mx, o, 64));
  __shared__ float redm[4], reds[4];
  const int wave = tid >> 6, lane = tid & 63;
  if (lane == 0) redm[wave] = mx;
  __syncthreads();
  mx = fmaxf(fmaxf(redm[0], redm[1]), fmaxf(redm[2], redm[3]));
  float sum = 0.f, ex[8];
#pragma unroll
  for (int s = 0; s < 8; ++s) { ex[s] = expf(sc[s] - mx); sum += ex[s]; }
#pragma unroll
  for (int o = 32; o >= 1; o >>= 1) sum += __shfl_xor(sum, o, 64);
  if (lane == 0) reds[wave] = sum;
  __syncthreads();
  sum = reds[0] + reds[1] + reds[2] + reds[3];
  float inv = 1.f / sum;
  float* orow = out + ((size_t)b * Nq + i) * Nq;
#pragma unroll
  for (int s = 0; s < 8; ++s) orow[s * 256 + tid] = ex[s] * inv;
}

extern "C" void kernel_launch(void* const* d_in, const int* in_sizes, int n_in,
                              void* d_out, int out_size, void* d_ws, size_t ws_size,
                              hipStream_t stream) {
  const float* x = (const float*)d_in[0];
  const int* adj = (const int*)d_in[1];
  const float* W = (const float*)d_in[2];
  const float* a = (const float*)d_in[3];
  float* out = (float*)d_out;

  char* ws = (char*)d_ws;
  size_t off = 0;
  auto alloc = [&](size_t bytes) -> void* {
    void* p = ws + off;
    off += (bytes + 255) & ~(size_t)255;
    return p;
  };
  float* w123 = (float*)alloc(3 * DINq * sizeof(float));
  float* WT = (float*)alloc((size_t)DINq * DINq * sizeof(float));
  float* tA = (float*)alloc((size_t)Bq * Nq * sizeof(float));
  float* siA = (float*)alloc((size_t)Bq * Nq * sizeof(float));
  float* sbA = (float*)alloc((size_t)Bq * Nq * sizeof(float));
  float* sjvA = (float*)alloc((size_t)Bq * Nq * sizeof(float));
  float* sjp = (float*)alloc((size_t)16 * Bq * Nq * sizeof(float));
  unsigned short* Xhi = (unsigned short*)alloc((size_t)Nq * Nq * 2);
  unsigned short* Xlo = (unsigned short*)alloc((size_t)Nq * Nq * 2);
  unsigned short* Mb = (unsigned short*)alloc((size_t)Nq * Nq * 2);
  unsigned* bm = (unsigned*)alloc((size_t)Nq * 64 * sizeof(unsigned));

  // MEASUREMENT ROUND: run the identical (round-5, idempotent) pipeline TWICE.
  // dur_R8 - dur_R5 = true kernel-sum K; separates fixed harness overhead.
#pragma unroll
  for (int rep = 0; rep < 2; ++rep) {
    k_prep<<<dim3(1), dim3(256), 0, stream>>>(W, a, w123);
    k_transposeW<<<dim3(DINq), dim3(DINq), 0, stream>>>(W, WT);
    k_hX<<<dim3(Nq / 32, Bq), dim3(256), 0, stream>>>(x, WT, w123, Xhi, Xlo, tA, siA, sbA);
    k_mask<<<dim3(Nq * 64 / 256), dim3(256), 0, stream>>>(adj, Mb, bm);
    k_gemm<<<dim3(512), dim3(256), 0, stream>>>(Mb, Xhi, Xlo, sjp);
    k_sjsum<<<dim3(Bq * Nq / 256), dim3(256), 0, stream>>>(sbA, tA, sjp, sjvA);
    k_softmax<<<dim3(Nq, Bq), dim3(256), 0, stream>>>(bm, siA, sjvA, out);
  }
}

// Round 9
// 134.428 us; speedup vs baseline: 2.0602x; 2.0602x over previous
//
#include <hip/hip_runtime.h>
#include <hip/hip_bf16.h>
#include <math.h>

#define Bq   8
#define DINq 256
#define Nq   2048

typedef __attribute__((ext_vector_type(8))) short bf16x8v;
typedef __attribute__((ext_vector_type(4))) float f32x4v;

__device__ __forceinline__ unsigned short f2bf(float f) {
  union { float f; unsigned u; } v; v.f = f;
  unsigned r = v.u + 0x7fffu + ((v.u >> 16) & 1u);
  return (unsigned short)(r >> 16);
}
__device__ __forceinline__ float bf2f(unsigned short h) {
  union { unsigned u; float f; } v; v.u = ((unsigned)h) << 16;
  return v.f;
}

__device__ __forceinline__ void gld_lds16(const void* g, void* l) {
  __builtin_amdgcn_global_load_lds(
      (const __attribute__((address_space(1))) unsigned int*)g,
      (__attribute__((address_space(3))) unsigned int*)l, 16, 0, 0);
}

// 8 mask bits -> 8 bf16 (1.0/0.0) packed as bf16x8v, element e = bit e.
__device__ __forceinline__ bf16x8v expand_mask(unsigned m8) {
  union { unsigned u[4]; bf16x8v v; } r;
  unsigned lo4 = ((m8 & 0xFu) * 0x204081u) & 0x01010101u;   // bytes b0..b3 = bits0..3
  unsigned hi4 = (((m8 >> 4) & 0xFu) * 0x204081u) & 0x01010101u;
  r.u[0] = ((lo4 & 0xFFu) | ((lo4 & 0xFF00u) << 8)) * 0x3F80u;
  r.u[1] = (((lo4 >> 16) & 0xFFu) | ((lo4 >> 24) << 16)) * 0x3F80u;
  r.u[2] = ((hi4 & 0xFFu) | ((hi4 & 0xFF00u) << 8)) * 0x3F80u;
  r.u[3] = (((hi4 >> 16) & 0xFFu) | ((hi4 >> 24) << 16)) * 0x3F80u;
  return r.v;
}

// ---- w123[k] = (W^T a1)[k], (W^T a2)[k], (W^T a3)[k] ----
__global__ void k_prep(const float* __restrict__ W, const float* __restrict__ a,
                       float* __restrict__ w123) {
  __shared__ float red[3][4][256];
  const int k = threadIdx.x & 255, dq = threadIdx.x >> 8;
  float s1 = 0.f, s2 = 0.f, s3 = 0.f;
  for (int d = dq * 64; d < dq * 64 + 64; ++d) {
    float w = W[d * DINq + k];
    s1 += w * a[d];
    s2 += w * a[DINq + d];
    s3 += w * a[2 * DINq + d];
  }
  red[0][dq][k] = s1; red[1][dq][k] = s2; red[2][dq][k] = s3;
  __syncthreads();
  if (threadIdx.x < 256) {
    w123[k]            = red[0][0][k] + red[0][1][k] + red[0][2][k] + red[0][3][k];
    w123[DINq + k]     = red[1][0][k] + red[1][1][k] + red[1][2][k] + red[1][3][k];
    w123[2 * DINq + k] = red[2][0][k] + red[2][1][k] + red[2][2][k] + red[2][3][k];
  }
}

// ---- WT[k][d] = W[d][k] ----
__global__ void k_transposeW(const float* __restrict__ W, float* __restrict__ WT) {
  int d = blockIdx.x, k = threadIdx.x;
  WT[(size_t)k * DINq + d] = W[(size_t)d * DINq + k];
}

// ---- X^T[(b,d)][i] = t[b,i]*h[b,i,d] hi/lo bf16; fused t/si/sb. (round-5) ----
__global__ __launch_bounds__(256, 2) void k_hX(const float* __restrict__ x,
                     const float* __restrict__ WT, const float* __restrict__ w123,
                     unsigned short* __restrict__ Xhi, unsigned short* __restrict__ Xlo,
                     float* __restrict__ tA, float* __restrict__ siA,
                     float* __restrict__ sbA) {
  __shared__ float xs[64][32];
  __shared__ float ws[64][128];
  __shared__ float wls[3][256];
  __shared__ float Pd[3][16][32];
  __shared__ float Tt[32];
  const int tid = threadIdx.x;
  const int iq = tid & 15;
  const int dg = tid >> 4;
  const int i0 = blockIdx.x * 32;
  const int b = blockIdx.y;

  for (int n = tid; n < 768; n += 256) ((float*)wls)[n] = w123[n];

  float p1[2] = {0.f, 0.f}, p2[2] = {0.f, 0.f}, p3[2] = {0.f, 0.f};

#pragma unroll
  for (int dh = 0; dh < 2; ++dh) {
    float acc[2][8];
#pragma unroll
    for (int aa = 0; aa < 2; ++aa)
#pragma unroll
      for (int cc = 0; cc < 8; ++cc) acc[aa][cc] = 0.f;

    for (int kc = 0; kc < 4; ++kc) {
      __syncthreads();
#pragma unroll
      for (int n = 0; n < 8; ++n) {
        int idx = n * 256 + tid;
        int kk = idx >> 5, ii = idx & 31;
        xs[kk][ii] = x[((size_t)b * DINq + kc * 64 + kk) * Nq + i0 + ii];
      }
#pragma unroll
      for (int n = 0; n < 8; ++n) {
        int idx = n * 256 + tid;
        int kk = idx >> 5, c4 = (idx & 31) * 4;
        *(f32x4v*)&ws[kk][c4] =
            *(const f32x4v*)&WT[(size_t)(kc * 64 + kk) * DINq + dh * 128 + c4];
      }
      __syncthreads();
#pragma unroll 4
      for (int kk = 0; kk < 64; ++kk) {
        float xv0 = xs[kk][iq * 2], xv1 = xs[kk][iq * 2 + 1];
        f32x4v w0 = *(const f32x4v*)&ws[kk][dg * 8];
        f32x4v w1 = *(const f32x4v*)&ws[kk][dg * 8 + 4];
#pragma unroll
        for (int cc = 0; cc < 4; ++cc) {
          acc[0][cc]     += xv0 * w0[cc];
          acc[0][cc + 4] += xv0 * w1[cc];
          acc[1][cc]     += xv1 * w0[cc];
          acc[1][cc + 4] += xv1 * w1[cc];
        }
      }
      if (dh == 0) {
#pragma unroll
        for (int kap = 0; kap < 4; ++kap) {
          int kk = dg * 4 + kap;
          float xv0 = xs[kk][iq * 2], xv1 = xs[kk][iq * 2 + 1];
          float w3 = wls[2][kc * 64 + kk];
          float w1v = wls[0][kc * 64 + kk], w2v = wls[1][kc * 64 + kk];
          p3[0] += xv0 * w3;  p3[1] += xv1 * w3;
          p1[0] += xv0 * w1v; p1[1] += xv1 * w1v;
          p2[0] += xv0 * w2v; p2[1] += xv1 * w2v;
        }
      }
    }

    if (dh == 0) {
#pragma unroll
      for (int aa = 0; aa < 2; ++aa) {
        Pd[0][dg][iq * 2 + aa] = p1[aa];
        Pd[1][dg][iq * 2 + aa] = p2[aa];
        Pd[2][dg][iq * 2 + aa] = p3[aa];
      }
      __syncthreads();
      if (tid < 32) {
        float t = 0.f, s1 = 0.f, s2 = 0.f;
#pragma unroll
        for (int g = 0; g < 16; ++g) {
          s1 += Pd[0][g][tid]; s2 += Pd[1][g][tid]; t += Pd[2][g][tid];
        }
        Tt[tid] = t;
        tA[(size_t)b * Nq + i0 + tid] = t;
        siA[(size_t)b * Nq + i0 + tid] = s1;
        sbA[(size_t)b * Nq + i0 + tid] = s2;
      }
      __syncthreads();
    }

    const float tv0 = Tt[iq * 2], tv1 = Tt[iq * 2 + 1];
#pragma unroll
    for (int cc = 0; cc < 8; ++cc) {
      int d = dh * 128 + dg * 8 + cc;
      float X0 = tv0 * acc[0][cc];
      float X1 = tv1 * acc[1][cc];
      unsigned short h0 = f2bf(X0), h1 = f2bf(X1);
      unsigned short l0 = f2bf(X0 - bf2f(h0)), l1 = f2bf(X1 - bf2f(h1));
      size_t xoff = ((size_t)b * DINq + d) * Nq + i0 + iq * 2;
      *(ushort2*)&Xhi[xoff] = make_ushort2(h0, h1);
      *(ushort2*)&Xlo[xoff] = make_ushort2(l0, l1);
    }
  }
}

// ---- bm[i][w] = bitmask of (adj[i][j]!=0), 32 j per word ----
__global__ void k_mask(const int* __restrict__ adj, unsigned* __restrict__ bm) {
  int wg = blockIdx.x * 256 + threadIdx.x;  // 2048 rows * 64 words
  int i = wg >> 6, w = wg & 63, j0 = w * 32;
  const int4* ap = (const int4*)&adj[(size_t)i * Nq + j0];
  unsigned bits = 0;
#pragma unroll
  for (int q = 0; q < 8; ++q) {
    int4 a = ap[q];
    if (a.x) bits |= 1u << (q * 4);
    if (a.y) bits |= 1u << (q * 4 + 1);
    if (a.z) bits |= 1u << (q * 4 + 2);
    if (a.w) bits |= 1u << (q * 4 + 3);
  }
  bm[wg] = bits;
}

// ---- GEMM: A = mask bits (LDS bitmask -> in-reg bf16 expansion, diag cleared),
//      B = Xhi AND Xlo (z merged into one acc), tile 256(M)x128(C), K-split x4,
//      ct-grouped per XCD for L2 residency, tri-buffer counted vmcnt,
//      fused sjv-partial epilogue ----
__global__ __launch_bounds__(256, 2) void k_gemm(const unsigned* __restrict__ bm,
                                                 const unsigned short* __restrict__ Xhi,
                                                 const unsigned short* __restrict__ Xlo,
                                                 float* __restrict__ sjp) {
  __shared__ __align__(16) unsigned short Bs[3][2][128 * 32];  // 48 KB
  __shared__ unsigned bmlds[256 * 16];                         // 16 KB
  const int tid = threadIdx.x;
  const int lane = tid & 63;
  const int wave = tid >> 6;
  const int wm = wave >> 1, wc = wave & 1;
  // ct-grouped decode: XCD x owns ct in {2x, 2x+1}; X working set 2MB -> L2.
  const int wg = blockIdx.x;
  const int xcd = wg & 7;
  const int sub = wg >> 3;            // [0,64)
  const int ct = xcd * 2 + (sub & 1);
  const int mt = (sub >> 1) & 7;
  const int ks = sub >> 4;            // [0,4)
  const int i0 = mt * 256, c0 = ct * 128, kbase = ks * 512;
  const int r15 = lane & 15, kg = lane >> 4;
  const int kb = 16 * (kg ^ ((r15 >> 1) & 3));  // B swizzle (as round-5)

  // --- stage mask bits: rows [i0,i0+256), words [kbase/32, +16), XOR-swizzled ---
  {
    const int kw0 = kbase >> 5;
#pragma unroll
    for (int n = 0; n < 4; ++n) {
      int idx4 = n * 256 + tid;
      int r = idx4 >> 2, w4 = (idx4 & 3) * 4;
      uint4 v = *(const uint4*)&bm[(size_t)(i0 + r) * 64 + kw0 + w4];
      bmlds[r * 16 + ((w4 + 0) ^ (r & 15))] = v.x;
      bmlds[r * 16 + ((w4 + 1) ^ (r & 15))] = v.y;
      bmlds[r * 16 + ((w4 + 2) ^ (r & 15))] = v.z;
      bmlds[r * 16 + ((w4 + 3) ^ (r & 15))] = v.w;
    }
  }
  __syncthreads();

  f32x4v acc[8][4];
#pragma unroll
  for (int m = 0; m < 8; ++m)
#pragma unroll
    for (int n = 0; n < 4; ++n) acc[m][n] = (f32x4v)0.f;

  auto STAGE = [&](int buf, int t) {
    const int k0 = kbase + t * 32;
#pragma unroll
    for (int l = 0; l < 2; ++l) {
      const int pc = l * 256 + tid;
      const int row = pc >> 2, q = pc & 3;
      const int kc = 8 * (q ^ ((row >> 1) & 3));
      gld_lds16(&Xhi[(size_t)(c0 + row) * Nq + k0 + kc], &Bs[buf][0][pc * 8]);
      gld_lds16(&Xlo[(size_t)(c0 + row) * Nq + k0 + kc], &Bs[buf][1][pc * 8]);
    }
  };

  constexpr int NT = 16;  // 512 / 32
  STAGE(0, 0);
  STAGE(1, 1);
  int cb = 0, sb2 = 2;
  for (int t = 0; t < NT; ++t) {
    if (t + 1 < NT) {
      asm volatile("s_waitcnt vmcnt(4)" ::: "memory");
    } else {
      asm volatile("s_waitcnt vmcnt(0)" ::: "memory");
    }
    __builtin_amdgcn_sched_barrier(0);
    __builtin_amdgcn_s_barrier();
    __builtin_amdgcn_sched_barrier(0);
    if (t + 2 < NT) STAGE(sb2, t + 2);

    const char* Bh = (const char*)&Bs[cb][0][0];
    const char* Bl = (const char*)&Bs[cb][1][0];
    bf16x8v bfh[4], bfl[4];
#pragma unroll
    for (int n = 0; n < 4; ++n) {
      bfh[n] = *(const bf16x8v*)(Bh + (wc * 64 + n * 16 + r15) * 64 + kb);
      bfl[n] = *(const bf16x8v*)(Bl + (wc * 64 + n * 16 + r15) * 64 + kb);
    }
    const int jb = kbase + t * 32 + kg * 8;
#pragma unroll
    for (int m = 0; m < 8; ++m) {
      const int arow = wm * 128 + m * 16 + r15;
      unsigned wv = bmlds[arow * 16 + (t ^ (arow & 15))];
      unsigned m8 = (wv >> (kg * 8)) & 0xFFu;
      unsigned d = (unsigned)(i0 + arow - jb);
      if (d < 8u) m8 &= ~(1u << d);          // i != j
      bf16x8v af = expand_mask(m8);
      __builtin_amdgcn_s_setprio(1);
#pragma unroll
      for (int n = 0; n < 4; ++n) {
        acc[m][n] = __builtin_amdgcn_mfma_f32_16x16x32_bf16(af, bfh[n], acc[m][n], 0, 0, 0);
        acc[m][n] = __builtin_amdgcn_mfma_f32_16x16x32_bf16(af, bfl[n], acc[m][n], 0, 0, 0);
      }
      __builtin_amdgcn_s_setprio(0);
    }
    cb = (cb == 2) ? 0 : cb + 1;
    sb2 = (sb2 == 2) ? 0 : sb2 + 1;
  }

  // Fused epilogue: partial = sum_d acc * (Xhi+Xlo); division by t in k_sjsum.
  const int b = c0 >> 8;
  const int re = (lane >> 4) * 4, ce = lane & 15;
  float s[8][4];
#pragma unroll
  for (int m = 0; m < 8; ++m)
#pragma unroll
    for (int r = 0; r < 4; ++r) s[m][r] = 0.f;
#pragma unroll
  for (int n = 0; n < 4; ++n) {
    const size_t xrow = (size_t)(c0 + wc * 64 + n * 16 + ce) * Nq;
#pragma unroll
    for (int m = 0; m < 8; ++m) {
      const size_t ib = xrow + i0 + wm * 128 + m * 16 + re;
      ushort4 xh = *(const ushort4*)&Xhi[ib];
      ushort4 xl = *(const ushort4*)&Xlo[ib];
      s[m][0] += acc[m][n][0] * (bf2f(xh.x) + bf2f(xl.x));
      s[m][1] += acc[m][n][1] * (bf2f(xh.y) + bf2f(xl.y));
      s[m][2] += acc[m][n][2] * (bf2f(xh.z) + bf2f(xl.z));
      s[m][3] += acc[m][n][3] * (bf2f(xh.w) + bf2f(xl.w));
    }
  }
#pragma unroll
  for (int o = 1; o < 16; o <<= 1) {
#pragma unroll
    for (int m = 0; m < 8; ++m)
#pragma unroll
      for (int r = 0; r < 4; ++r) s[m][r] += __shfl_xor(s[m][r], o, 64);
  }
  if (ce == 0) {
    const int slice = (ct & 1) * 8 + ks * 2 + wc;
    float* sp = sjp + ((size_t)slice * Bq + b) * Nq;
#pragma unroll
    for (int m = 0; m < 8; ++m)
#pragma unroll
      for (int r = 0; r < 4; ++r)
        sp[i0 + wm * 128 + m * 16 + re + r] = s[m][r];
  }
}

// ---- sjv[b,i] = sb[b,i] + (sum of 16 partial slices) / t[b,i] ----
__global__ void k_sjsum(const float* __restrict__ sbA, const float* __restrict__ tA,
                        const float* __restrict__ sjp, float* __restrict__ sjvA) {
  int idx = blockIdx.x * 256 + threadIdx.x;
  float s = 0.f;
#pragma unroll
  for (int sl = 0; sl < 16; ++sl) s += sjp[(size_t)sl * Bq * Nq + idx];
  sjvA[idx] = sbA[idx] + s / tA[idx];
}

// ---- out[b,i,:] = softmax_j( mask(bm, lrelu(si[b,i] + sjv[b,j])) ) ----
__global__ void k_softmax(const unsigned* __restrict__ bm, const float* __restrict__ siA,
                          const float* __restrict__ sjvA, float* __restrict__ out) {
  const int b = blockIdx.y, i = blockIdx.x, tid = threadIdx.x;
  const float siv = siA[(size_t)b * Nq + i];
  const unsigned* brow = bm + (size_t)i * 64;
  const float* sjb = sjvA + (size_t)b * Nq;
  const int bit = tid & 31;
  float sc[8];
  float mx = -3.0e38f;
#pragma unroll
  for (int s = 0; s < 8; ++s) {
    int j = s * 256 + tid;
    float v = siv + sjb[j];
    v = v > 0.f ? v : 0.2f * v;
    unsigned wv = brow[j >> 5];
    v = ((wv >> bit) & 1u) ? v : -9.0e15f;
    sc[s] = v;
    mx = fmaxf(mx, v);
  }
#pragma unroll
  for (int o = 32; o >= 1; o >>= 1) mx = fmaxf(mx, __shfl_xor(mx, o, 64));
  __shared__ float redm[4], reds[4];
  const int wave = tid >> 6, lane = tid & 63;
  if (lane == 0) redm[wave] = mx;
  __syncthreads();
  mx = fmaxf(fmaxf(redm[0], redm[1]), fmaxf(redm[2], redm[3]));
  float sum = 0.f, ex[8];
#pragma unroll
  for (int s = 0; s < 8; ++s) { ex[s] = expf(sc[s] - mx); sum += ex[s]; }
#pragma unroll
  for (int o = 32; o >= 1; o >>= 1) sum += __shfl_xor(sum, o, 64);
  if (lane == 0) reds[wave] = sum;
  __syncthreads();
  sum = reds[0] + reds[1] + reds[2] + reds[3];
  float inv = 1.f / sum;
  float* orow = out + ((size_t)b * Nq + i) * Nq;
#pragma unroll
  for (int s = 0; s < 8; ++s) orow[s * 256 + tid] = ex[s] * inv;
}

extern "C" void kernel_launch(void* const* d_in, const int* in_sizes, int n_in,
                              void* d_out, int out_size, void* d_ws, size_t ws_size,
                              hipStream_t stream) {
  const float* x = (const float*)d_in[0];
  const int* adj = (const int*)d_in[1];
  const float* W = (const float*)d_in[2];
  const float* a = (const float*)d_in[3];
  float* out = (float*)d_out;

  char* ws = (char*)d_ws;
  size_t off = 0;
  auto alloc = [&](size_t bytes) -> void* {
    void* p = ws + off;
    off += (bytes + 255) & ~(size_t)255;
    return p;
  };
  float* w123 = (float*)alloc(3 * DINq * sizeof(float));
  float* WT = (float*)alloc((size_t)DINq * DINq * sizeof(float));
  float* tA = (float*)alloc((size_t)Bq * Nq * sizeof(float));
  float* siA = (float*)alloc((size_t)Bq * Nq * sizeof(float));
  float* sbA = (float*)alloc((size_t)Bq * Nq * sizeof(float));
  float* sjvA = (float*)alloc((size_t)Bq * Nq * sizeof(float));
  float* sjp = (float*)alloc((size_t)16 * Bq * Nq * sizeof(float));
  unsigned short* Xhi = (unsigned short*)alloc((size_t)Nq * Nq * 2);
  unsigned short* Xlo = (unsigned short*)alloc((size_t)Nq * Nq * 2);
  unsigned* bm = (unsigned*)alloc((size_t)Nq * 64 * sizeof(unsigned));

  k_prep<<<dim3(1), dim3(1024), 0, stream>>>(W, a, w123);
  k_transposeW<<<dim3(DINq), dim3(DINq), 0, stream>>>(W, WT);
  k_hX<<<dim3(Nq / 32, Bq), dim3(256), 0, stream>>>(x, WT, w123, Xhi, Xlo, tA, siA, sbA);
  k_mask<<<dim3(Nq * 64 / 256), dim3(256), 0, stream>>>(adj, bm);
  k_gemm<<<dim3(512), dim3(256), 0, stream>>>(bm, Xhi, Xlo, sjp);
  k_sjsum<<<dim3(Bq * Nq / 256), dim3(256), 0, stream>>>(sbA, tA, sjp, sjvA);
  k_softmax<<<dim3(Nq, Bq), dim3(256), 0, stream>>>(bm, siA, sjvA, out);
}